// Round 2
// baseline (184.015 us; speedup 1.0000x reference)
//
#include <hip/hip_runtime.h>
#include <cmath>

#define HW   35200          // 200*176
#define CD   128            // C*D

// ---- workspace float offsets ----
#define OFF_W1F   0         // w1ft[c][o]   64*64
#define OFF_TD    4096      // tD[o][d]     64*2
#define OFF_TH    4224      // tH[o][h]     64*200
#define OFF_TW    17024     // tW[o][w]     64*176
#define OFF_W2F   28288     // w2ft[c][o2]  64*32
#define OFF_B2F   30336     // 32
#define OFF_W3F   30368     // 32
#define OFF_F1    30720     // f1 [n][32][HW][4]  (18,022,400 floats)

struct Smem {
  float h1[64][64];      // 16 KB: one depth's layer-1 activations
  float lgp[2][4][64];   // 2 KB : per-wave partial logits
  float wt[2][64];       // 0.5 KB
};

__device__ __forceinline__ float lrelu(float v) { return v >= 0.f ? v : 0.01f * v; }

// ---------------- setup: fold BN into weights, build separable PE tables ----------------
__global__ void setup_kernel(const float* __restrict__ w1, const float* __restrict__ b1,
                             const float* __restrict__ g1, const float* __restrict__ be1,
                             const float* __restrict__ w2, const float* __restrict__ b2,
                             const float* __restrict__ g2, const float* __restrict__ be2,
                             const float* __restrict__ w3, const float* __restrict__ b3,
                             float* __restrict__ ws) {
  const float RS = rsqrtf(1.0f + 1e-5f);
  int i = blockIdx.x * blockDim.x + threadIdx.x;
  if (i < 4096) {                       // w1ft[c][o] = w1[o][c] * s1[o]
    int c = i >> 6, o = i & 63;
    ws[OFF_W1F + i] = w1[o*112 + c] * (g1[o] * RS);
    return;
  }
  i -= 4096;
  if (i < 128) {                        // tD[o][d] = s1*(b1 + w1[64..79]·encD(d)) + be1
    int o = i >> 1, d = i & 1;
    float a = 0.f;
    for (int j = 0; j < 8; ++j) {
      float dv = expf((float)(2*j) * (-0.5756462732485115f));
      float t  = (float)d * dv;
      a += w1[o*112 + 64 + j] * sinf(t) + w1[o*112 + 72 + j] * cosf(t);
    }
    ws[OFF_TD + i] = (g1[o]*RS) * (b1[o] + a) + be1[o];
    return;
  }
  i -= 128;
  if (i < 12800) {                      // tH[o][h] = s1 * w1[80..95]·encH(h)
    int o = i / 200, h = i - o*200;
    float a = 0.f;
    for (int j = 0; j < 8; ++j) {
      float dv = expf((float)(2*j) * (-0.5756462732485115f));
      float t  = (float)h * dv;
      a += w1[o*112 + 80 + j] * sinf(t) + w1[o*112 + 88 + j] * cosf(t);
    }
    ws[OFF_TH + i] = (g1[o]*RS) * a;
    return;
  }
  i -= 12800;
  if (i < 11264) {                      // tW[o][w] = s1 * w1[96..111]·encW(w)
    int o = i / 176, w = i - o*176;
    float a = 0.f;
    for (int j = 0; j < 8; ++j) {
      float dv = expf((float)(2*j) * (-0.5756462732485115f));
      float t  = (float)w * dv;
      a += w1[o*112 + 96 + j] * sinf(t) + w1[o*112 + 104 + j] * cosf(t);
    }
    ws[OFF_TW + i] = (g1[o]*RS) * a;
    return;
  }
  i -= 11264;
  if (i < 2048) {                       // w2ft[c][o2] = w2[o2][c] * s2[o2]
    int c = i >> 5, o = i & 31;
    ws[OFF_W2F + i] = w2[o*64 + c] * (g2[o] * RS);
    return;
  }
  i -= 2048;
  if (i < 32) { ws[OFF_B2F + i] = b2[i]*(g2[i]*RS) + be2[i]; return; }
  i -= 32;
  if (i < 32) { ws[OFF_W3F + i] = w3[i]; return; }
}

// ---------------- shared dvf core: computes depth weights wt[2][64] for a 64-pixel tile ----------------
__device__ __forceinline__ void dvf_weights(const float* __restrict__ xn,
                                            const float* __restrict__ wtab,
                                            Smem& s, int hw0) {
  const int px  = threadIdx.x & 63;
  const int wid = __builtin_amdgcn_readfirstlane(threadIdx.x >> 6);  // uniform wave id
  const int hw  = hw0 + px;
  const int h   = hw / 176;
  const int w   = hw - h * 176;
  const int og  = wid * 16;
  const int o2g = wid * 8;

#pragma unroll
  for (int d = 0; d < 2; ++d) {
    // ---- layer 1: 64 -> 64, one depth (wave computes 16 output channels, lanes = pixels) ----
    float acc[16];
#pragma unroll
    for (int oi = 0; oi < 16; ++oi) {
      const int o = og + oi;
      acc[oi] = wtab[OFF_TD + o*2 + d] + wtab[OFF_TH + o*200 + h] + wtab[OFF_TW + o*176 + w];
    }
#pragma unroll 4
    for (int c = 0; c < 64; ++c) {
      const float xv = xn[(c*2 + d)*HW + hw];
      const float* wr = wtab + OFF_W1F + c*64 + og;   // wave-uniform -> s_load
#pragma unroll
      for (int oi = 0; oi < 16; ++oi)
        acc[oi] = fmaf(wr[oi], xv, acc[oi]);
    }
#pragma unroll
    for (int oi = 0; oi < 16; ++oi)
      s.h1[og + oi][px] = lrelu(acc[oi]);
    __syncthreads();

    // ---- layer 2: 64 -> 32 (wave computes 8 output channels) + fold layer 3 into partial logit ----
    float acc2[8];
#pragma unroll
    for (int oi = 0; oi < 8; ++oi)
      acc2[oi] = wtab[OFF_B2F + o2g + oi];
#pragma unroll 4
    for (int c = 0; c < 64; ++c) {
      const float a = s.h1[c][px];
      const float* wr = wtab + OFF_W2F + c*32 + o2g;  // wave-uniform -> s_load
#pragma unroll
      for (int oi = 0; oi < 8; ++oi)
        acc2[oi] = fmaf(wr[oi], a, acc2[oi]);
    }
    float lp = 0.f;
#pragma unroll
    for (int oi = 0; oi < 8; ++oi)
      lp = fmaf(wtab[OFF_W3F + o2g + oi], lrelu(acc2[oi]), lp);
    s.lgp[d][wid][px] = lp;
    __syncthreads();   // h1 consumption done before next depth overwrites; lgp visible
  }

  // ---- softmax over the 2 depths (b3 cancels in the logit difference) ----
  if (threadIdx.x < 128) {
    const int d = threadIdx.x >> 6;
    const int p = threadIdx.x & 63;
    const float l0 = s.lgp[0][0][p] + s.lgp[0][1][p] + s.lgp[0][2][p] + s.lgp[0][3][p];
    const float l1 = s.lgp[1][0][p] + s.lgp[1][1][p] + s.lgp[1][2][p] + s.lgp[1][3][p];
    const float ld = d ? l1 : l0;
    const float lo = d ? l0 : l1;
    s.wt[d][p] = 1.f / (1.f + expf(lo - ld));
  }
  __syncthreads();
}

// ---------------- pass 1: f1 = dvf(x1), stored as [n][cd/4][hw][4] ----------------
__global__ __launch_bounds__(256)
void dvf_f1_kernel(const float* __restrict__ x,
                   const float* __restrict__ wtab,
                   float* __restrict__ f1out) {
  __shared__ Smem s;
  const int n   = blockIdx.y;
  const int hw0 = blockIdx.x * 64;
  const float* xn = x + (size_t)n * CD * HW;
  dvf_weights(xn, wtab, s, hw0);

  const int px  = threadIdx.x & 63;
  const int wid = threadIdx.x >> 6;
  const int hw  = hw0 + px;
  const float w0  = s.wt[0][px];
  const float w1v = s.wt[1][px];
#pragma unroll
  for (int i = 0; i < 8; ++i) {
    const int cd4 = wid*8 + i;
    const int cd0 = cd4*4;          // cd = c*2+d matches x's [c][d] flattening
    float4 v;
    v.x = xn[(cd0+0)*HW + hw] * w0;
    v.y = xn[(cd0+1)*HW + hw] * w1v;
    v.z = xn[(cd0+2)*HW + hw] * w0;
    v.w = xn[(cd0+3)*HW + hw] * w1v;
    *(float4*)(f1out + (((size_t)n*32 + cd4)*HW + hw)*4) = v;
  }
}

// ---------------- pass 2: out = max(dvf(x0), bilinear(rot(f1))) ----------------
__global__ __launch_bounds__(256)
void dvf_align_kernel(const float* __restrict__ x,
                      const float* __restrict__ wtab,
                      const float* __restrict__ f1,
                      const float* __restrict__ tp,
                      float* __restrict__ out) {
  __shared__ Smem s;
  const int n   = blockIdx.y;
  const int hw0 = blockIdx.x * 64;
  const float* xn = x + (size_t)n * CD * HW;
  dvf_weights(xn, wtab, s, hw0);

  const int px  = threadIdx.x & 63;
  const int wid = threadIdx.x >> 6;
  const int hw  = hw0 + px;
  const int h   = hw / 176;
  const int w   = hw - h * 176;
  const float w0  = s.wt[0][px];
  const float w1v = s.wt[1][px];

  // rotated sample position (faithful two-step rotation like the reference)
  const float thp = tp[n*2 + 0], thc = tp[n*2 + 1];
  const float gx = 0.2f + 0.4f * (float)w;
  const float gy = -39.8f + 0.4f * (float)h;
  const float c1 = cosf(thc),  s1v = sinf(thc);
  const float p1x = gx*c1 - gy*s1v;
  const float p1y = gx*s1v + gy*c1;
  const float c2 = cosf(-thp), s2v = sinf(-thp);
  const float p2x = p1x*c2 - p1y*s2v;
  const float p2y = p1x*s2v + p1y*c2;
  const float xi = p2x / 0.05f / 8.f;
  const float yi = (p2y - (-40.f)) / 0.05f / 8.f;

  const float xf = floorf(xi), yf = floorf(yi);
  const int x0i = (int)xf, y0i = (int)yf;
  const int x0c = min(max(x0i,     0), 175);
  const int x1c = min(max(x0i + 1, 0), 175);
  const int y0c = min(max(y0i,     0), 199);
  const int y1c = min(max(y0i + 1, 0), 199);
  const float x0f = (float)x0c, x1f = (float)x1c;
  const float y0f = (float)y0c, y1f = (float)y1c;
  const float wa = (x1f - xi) * (y1f - yi);
  const float wb = (x1f - xi) * (yi - y0f);
  const float wc = (xi - x0f) * (y1f - yi);
  const float wd = (xi - x0f) * (yi - y0f);
  const int ta = y0c*176 + x0c, tb = y1c*176 + x0c;
  const int tc = y0c*176 + x1c, td = y1c*176 + x1c;

#pragma unroll
  for (int i = 0; i < 8; ++i) {
    const int cd4 = wid*8 + i;
    const int cd0 = cd4*4;
    const float* fb = f1 + ((size_t)n*32 + cd4)*HW*4;
    const float4 Ia = *(const float4*)(fb + (size_t)ta*4);
    const float4 Ib = *(const float4*)(fb + (size_t)tb*4);
    const float4 Ic = *(const float4*)(fb + (size_t)tc*4);
    const float4 Id = *(const float4*)(fb + (size_t)td*4);
    float4 sv;
    sv.x = Ia.x*wa + Ib.x*wb + Ic.x*wc + Id.x*wd;
    sv.y = Ia.y*wa + Ib.y*wb + Ic.y*wc + Id.y*wd;
    sv.z = Ia.z*wa + Ib.z*wb + Ic.z*wc + Id.z*wd;
    sv.w = Ia.w*wa + Ib.w*wb + Ic.w*wc + Id.w*wd;

    const float f00 = xn[(cd0+0)*HW + hw] * w0;
    const float f01 = xn[(cd0+1)*HW + hw] * w1v;
    const float f02 = xn[(cd0+2)*HW + hw] * w0;
    const float f03 = xn[(cd0+3)*HW + hw] * w1v;

    float* op = out + ((size_t)n*CD + cd0)*HW + hw;
    op[0]            = fmaxf(f00, sv.x);
    op[HW]           = fmaxf(f01, sv.y);
    op[2*(size_t)HW] = fmaxf(f02, sv.z);
    op[3*(size_t)HW] = fmaxf(f03, sv.w);
  }
}

extern "C" void kernel_launch(void* const* d_in, const int* in_sizes, int n_in,
                              void* d_out, int out_size, void* d_ws, size_t ws_size,
                              hipStream_t stream) {
  const float* x0  = (const float*)d_in[0];
  const float* x1  = (const float*)d_in[1];
  const float* tp  = (const float*)d_in[2];
  const float* w1  = (const float*)d_in[3];
  const float* b1  = (const float*)d_in[4];
  const float* g1  = (const float*)d_in[5];
  const float* be1 = (const float*)d_in[6];
  const float* w2  = (const float*)d_in[7];
  const float* b2  = (const float*)d_in[8];
  const float* g2  = (const float*)d_in[9];
  const float* be2 = (const float*)d_in[10];
  const float* w3  = (const float*)d_in[11];
  const float* b3  = (const float*)d_in[12];
  float* ws = (float*)d_ws;

  setup_kernel<<<119, 256, 0, stream>>>(w1, b1, g1, be1, w2, b2, g2, be2, w3, b3, ws);

  dim3 grid(550, 4);   // 35200/64 chunks x N
  dvf_f1_kernel<<<grid, 256, 0, stream>>>(x1, ws, ws + OFF_F1);
  dvf_align_kernel<<<grid, 256, 0, stream>>>(x0, ws, ws + OFF_F1, tp, (float*)d_out);
}

// Round 3
// 173.922 us; speedup vs baseline: 1.0580x; 1.0580x over previous
//
#include <hip/hip_runtime.h>
#include <cmath>

#define HW   35200          // 200*176
#define CD   128            // C*D

// ---- workspace float offsets ----
#define OFF_W1F   0         // w1ft[c][o]   64*64  (transposed, BN-folded)
#define OFF_TD    4096      // tD[d][o]     2*64
#define OFF_TH    4224      // tH[o][h]     64*200
#define OFF_TW    17024     // tW[o][w]     64*176
#define OFF_W2F   28288     // w2f[o2][c]   32*64  (natural layout, BN-folded)
#define OFF_B2F   30336     // 32
#define OFF_W3F   30368     // 32
#define OFF_WT    30400     // wtT[d][n][hw]  2*4*HW = 281600
#define OFF_F1    312000    // f1 [n][32][HW][4]  (18,022,400 floats)

__device__ __forceinline__ float lrelu(float v) { return v >= 0.f ? v : 0.01f * v; }

// ---------------- setup: fold BN into weights, build separable PE tables ----------------
__global__ void setup_kernel(const float* __restrict__ w1, const float* __restrict__ b1,
                             const float* __restrict__ g1, const float* __restrict__ be1,
                             const float* __restrict__ w2, const float* __restrict__ b2,
                             const float* __restrict__ g2, const float* __restrict__ be2,
                             const float* __restrict__ w3, const float* __restrict__ b3,
                             float* __restrict__ ws) {
  const float RS = rsqrtf(1.0f + 1e-5f);
  int i = blockIdx.x * blockDim.x + threadIdx.x;
  if (i < 4096) {                       // w1ft[c][o] = w1[o][c] * s1[o]
    int c = i >> 6, o = i & 63;
    ws[OFF_W1F + i] = w1[o*112 + c] * (g1[o] * RS);
    return;
  }
  i -= 4096;
  if (i < 128) {                        // tD[d][o] = s1*(b1 + w1[64..79]·encD(d)) + be1
    int d = i >> 6, o = i & 63;
    float a = 0.f;
    for (int j = 0; j < 8; ++j) {
      float dv = expf((float)(2*j) * (-0.5756462732485115f));
      float t  = (float)d * dv;
      a += w1[o*112 + 64 + j] * sinf(t) + w1[o*112 + 72 + j] * cosf(t);
    }
    ws[OFF_TD + d*64 + o] = (g1[o]*RS) * (b1[o] + a) + be1[o];
    return;
  }
  i -= 128;
  if (i < 12800) {                      // tH[o][h] = s1 * w1[80..95]·encH(h)
    int o = i / 200, h = i - o*200;
    float a = 0.f;
    for (int j = 0; j < 8; ++j) {
      float dv = expf((float)(2*j) * (-0.5756462732485115f));
      float t  = (float)h * dv;
      a += w1[o*112 + 80 + j] * sinf(t) + w1[o*112 + 88 + j] * cosf(t);
    }
    ws[OFF_TH + i] = (g1[o]*RS) * a;
    return;
  }
  i -= 12800;
  if (i < 11264) {                      // tW[o][w] = s1 * w1[96..111]·encW(w)
    int o = i / 176, w = i - o*176;
    float a = 0.f;
    for (int j = 0; j < 8; ++j) {
      float dv = expf((float)(2*j) * (-0.5756462732485115f));
      float t  = (float)w * dv;
      a += w1[o*112 + 96 + j] * sinf(t) + w1[o*112 + 104 + j] * cosf(t);
    }
    ws[OFF_TW + i] = (g1[o]*RS) * a;
    return;
  }
  i -= 11264;
  if (i < 2048) {                       // w2f[o2][c] = w2[o2][c] * s2[o2]  (natural layout)
    ws[OFF_W2F + i] = w2[i] * (g2[i >> 6] * RS);
    return;
  }
  i -= 2048;
  if (i < 32) { ws[OFF_B2F + i] = b2[i]*(g2[i]*RS) + be2[i]; return; }
  i -= 32;
  if (i < 32) { ws[OFF_W3F + i] = w3[i]; }
}

// ---------------- pass 1: MLP for BOTH inputs; thread = (pixel, depth) ----------------
// i=1 (x1): writes f1 = x1 * wt1, layout [n][cd4][hw][4]
// i=0 (x0): writes wtT[d][n][hw]
__global__ __launch_bounds__(256)
void mlp_kernel(const float* __restrict__ x0, const float* __restrict__ x1,
                const float* __restrict__ wtab, float* __restrict__ f1out,
                float* __restrict__ wtT) {
  __shared__ float lg_s[2][128];
  const int tix = threadIdx.x;
  const int pxl = tix & 127;
  const int d   = __builtin_amdgcn_readfirstlane(tix >> 7);   // wave-uniform depth
  const int n   = blockIdx.y;
  const int inp = blockIdx.z;
  const int hw  = blockIdx.x * 128 + pxl;                     // 275*128 == HW exactly
  const int h   = hw / 176;
  const int w   = hw - h * 176;
  const float* xn = (inp ? x1 : x0) + (size_t)n * CD * HW;

  // ---- layer 1: 64 -> 64, all channels in registers ----
  const float* tD = wtab + OFF_TD + d * 64;                   // s_load (uniform)
  float h1[64];
#pragma unroll
  for (int o = 0; o < 64; ++o)
    h1[o] = tD[o] + wtab[OFF_TH + o*200 + h] + wtab[OFF_TW + o*176 + w];

#pragma unroll 2
  for (int c = 0; c < 64; ++c) {
    const float xv = xn[(size_t)(c*2 + d)*HW + hw];
    const float* wr = wtab + OFF_W1F + c*64;                  // wave-uniform -> s_load
#pragma unroll
    for (int o = 0; o < 64; ++o)
      h1[o] = fmaf(wr[o], xv, h1[o]);
  }
#pragma unroll
  for (int o = 0; o < 64; ++o) h1[o] = lrelu(h1[o]);

  // ---- layer 2 + 3 folded: logit ----
  float lg = 0.f;
#pragma unroll 2
  for (int o2 = 0; o2 < 32; ++o2) {
    float a = wtab[OFF_B2F + o2];
    const float* wr = wtab + OFF_W2F + o2*64;                 // wave-uniform -> s_load
#pragma unroll
    for (int c = 0; c < 64; ++c)
      a = fmaf(wr[c], h1[c], a);
    lg = fmaf(wtab[OFF_W3F + o2], lrelu(a), lg);
  }

  // ---- exchange logits across depth, softmax ----
  lg_s[d][pxl] = lg;
  __syncthreads();
  const float lgo = lg_s[1 - d][pxl];

  if (inp == 0) {
    wtT[(size_t)(d*4 + n)*HW + hw] = 1.f / (1.f + expf(lgo - lg));
  } else {
    const float wme = 1.f / (1.f + expf(lgo - lg));
    const float wot = 1.f / (1.f + expf(lg - lgo));
    const float w0  = d ? wot : wme;
    const float w1v = d ? wme : wot;
#pragma unroll
    for (int ii = 0; ii < 16; ++ii) {
      const int k = d*16 + ii, cd0 = k*4;
      float4 v;
      v.x = xn[(size_t)(cd0+0)*HW + hw] * w0;
      v.y = xn[(size_t)(cd0+1)*HW + hw] * w1v;
      v.z = xn[(size_t)(cd0+2)*HW + hw] * w0;
      v.w = xn[(size_t)(cd0+3)*HW + hw] * w1v;
      *(float4*)(f1out + (((size_t)n*32 + k)*HW + hw)*4) = v;
    }
  }
}

// ---------------- pass 2: pure memory — out = max(x0*wt0, bilinear(rot(f1))) ----------------
__global__ __launch_bounds__(256)
void gather_max_kernel(const float* __restrict__ x0,
                       const float* __restrict__ f1,
                       const float* __restrict__ wtT,
                       const float* __restrict__ tp,
                       float* __restrict__ out) {
  const int tix = threadIdx.x;
  const int px  = tix & 63;
  const int q   = tix >> 6;
  const int n   = blockIdx.y;
  const int hw  = blockIdx.x * 64 + px;
  const int h   = hw / 176;
  const int w   = hw - h * 176;
  const float* xn = x0 + (size_t)n * CD * HW;
  const float w0  = wtT[(size_t)(0 + n)*HW + hw];
  const float w1v = wtT[(size_t)(4 + n)*HW + hw];

  // rotated sample position (faithful two-step rotation like the reference)
  const float thp = tp[n*2 + 0], thc = tp[n*2 + 1];
  const float gx = 0.2f + 0.4f * (float)w;
  const float gy = -39.8f + 0.4f * (float)h;
  const float c1 = cosf(thc),  s1v = sinf(thc);
  const float p1x = gx*c1 - gy*s1v;
  const float p1y = gx*s1v + gy*c1;
  const float c2 = cosf(-thp), s2v = sinf(-thp);
  const float p2x = p1x*c2 - p1y*s2v;
  const float p2y = p1x*s2v + p1y*c2;
  const float xi = p2x / 0.05f / 8.f;
  const float yi = (p2y - (-40.f)) / 0.05f / 8.f;

  const float xf = floorf(xi), yf = floorf(yi);
  const int x0i = (int)xf, y0i = (int)yf;
  const int x0c = min(max(x0i,     0), 175);
  const int x1c = min(max(x0i + 1, 0), 175);
  const int y0c = min(max(y0i,     0), 199);
  const int y1c = min(max(y0i + 1, 0), 199);
  const float x0f = (float)x0c, x1f = (float)x1c;
  const float y0f = (float)y0c, y1f = (float)y1c;
  const float wa = (x1f - xi) * (y1f - yi);
  const float wb = (x1f - xi) * (yi - y0f);
  const float wc = (xi - x0f) * (y1f - yi);
  const float wd = (xi - x0f) * (yi - y0f);
  const int ta = y0c*176 + x0c, tb = y1c*176 + x0c;
  const int tc = y0c*176 + x1c, td = y1c*176 + x1c;

#pragma unroll
  for (int i = 0; i < 8; ++i) {
    const int cd4 = q*8 + i;
    const int cd0 = cd4*4;
    const float* fb = f1 + ((size_t)n*32 + cd4)*HW*4;
    const float4 Ia = *(const float4*)(fb + (size_t)ta*4);
    const float4 Ib = *(const float4*)(fb + (size_t)tb*4);
    const float4 Ic = *(const float4*)(fb + (size_t)tc*4);
    const float4 Id = *(const float4*)(fb + (size_t)td*4);
    float4 sv;
    sv.x = Ia.x*wa + Ib.x*wb + Ic.x*wc + Id.x*wd;
    sv.y = Ia.y*wa + Ib.y*wb + Ic.y*wc + Id.y*wd;
    sv.z = Ia.z*wa + Ib.z*wb + Ic.z*wc + Id.z*wd;
    sv.w = Ia.w*wa + Ib.w*wb + Ic.w*wc + Id.w*wd;

    const float f00 = xn[(size_t)(cd0+0)*HW + hw] * w0;
    const float f01 = xn[(size_t)(cd0+1)*HW + hw] * w1v;
    const float f02 = xn[(size_t)(cd0+2)*HW + hw] * w0;
    const float f03 = xn[(size_t)(cd0+3)*HW + hw] * w1v;

    float* op = out + ((size_t)n*CD + cd0)*HW + hw;
    op[0]            = fmaxf(f00, sv.x);
    op[HW]           = fmaxf(f01, sv.y);
    op[2*(size_t)HW] = fmaxf(f02, sv.z);
    op[3*(size_t)HW] = fmaxf(f03, sv.w);
  }
}

extern "C" void kernel_launch(void* const* d_in, const int* in_sizes, int n_in,
                              void* d_out, int out_size, void* d_ws, size_t ws_size,
                              hipStream_t stream) {
  const float* x0  = (const float*)d_in[0];
  const float* x1  = (const float*)d_in[1];
  const float* tp  = (const float*)d_in[2];
  const float* w1  = (const float*)d_in[3];
  const float* b1  = (const float*)d_in[4];
  const float* g1  = (const float*)d_in[5];
  const float* be1 = (const float*)d_in[6];
  const float* w2  = (const float*)d_in[7];
  const float* b2  = (const float*)d_in[8];
  const float* g2  = (const float*)d_in[9];
  const float* be2 = (const float*)d_in[10];
  const float* w3  = (const float*)d_in[11];
  const float* b3  = (const float*)d_in[12];
  float* ws = (float*)d_ws;

  setup_kernel<<<119, 256, 0, stream>>>(w1, b1, g1, be1, w2, b2, g2, be2, w3, b3, ws);

  dim3 g1d(275, 4, 2);   // 128 px per block, n, input
  mlp_kernel<<<g1d, 256, 0, stream>>>(x0, x1, ws, ws + OFF_F1, ws + OFF_WT);

  dim3 g2d(550, 4);      // 64 px per block x 4 channel-quarters, n
  gather_max_kernel<<<g2d, 256, 0, stream>>>(x0, ws + OFF_F1, ws + OFF_WT, tp, (float*)d_out);
}

// Round 4
// 161.952 us; speedup vs baseline: 1.1362x; 1.0739x over previous
//
#include <hip/hip_runtime.h>
#include <cmath>

#define HW   35200          // 200*176
#define CD   128            // C*D

// ---- workspace float offsets ----
#define OFF_W1F   0         // w1ft[c][o]   64*64  (transposed, BN-folded)
#define OFF_TD    4096      // tD[d][o]     2*64
#define OFF_TH    4224      // tH[o][h]     64*200
#define OFF_TW    17024     // tW[o][w]     64*176
#define OFF_W2F   28288     // w2ft[c][o2]  64*32  (transposed, BN-folded)
#define OFF_B2F   30336     // 32
#define OFF_W3F   30368     // 32
#define OFF_WT    30400     // wtT[d][n][hw]  2*4*HW = 281600
#define OFF_F1    312000    // f1 [n][32][HW][4]  (18,022,400 floats)

__device__ __forceinline__ float lrelu(float v) { return v >= 0.f ? v : 0.01f * v; }

// ---------------- setup: fold BN into weights, build separable PE tables ----------------
__global__ void setup_kernel(const float* __restrict__ w1, const float* __restrict__ b1,
                             const float* __restrict__ g1, const float* __restrict__ be1,
                             const float* __restrict__ w2, const float* __restrict__ b2,
                             const float* __restrict__ g2, const float* __restrict__ be2,
                             const float* __restrict__ w3, const float* __restrict__ b3,
                             float* __restrict__ ws) {
  const float RS = rsqrtf(1.0f + 1e-5f);
  int i = blockIdx.x * blockDim.x + threadIdx.x;
  if (i < 4096) {                       // w1ft[c][o] = w1[o][c] * s1[o]
    int c = i >> 6, o = i & 63;
    ws[OFF_W1F + i] = w1[o*112 + c] * (g1[o] * RS);
    return;
  }
  i -= 4096;
  if (i < 128) {                        // tD[d][o] = s1*(b1 + w1[64..79]·encD(d)) + be1
    int d = i >> 6, o = i & 63;
    float a = 0.f;
    for (int j = 0; j < 8; ++j) {
      float dv = expf((float)(2*j) * (-0.5756462732485115f));
      float t  = (float)d * dv;
      a += w1[o*112 + 64 + j] * sinf(t) + w1[o*112 + 72 + j] * cosf(t);
    }
    ws[OFF_TD + d*64 + o] = (g1[o]*RS) * (b1[o] + a) + be1[o];
    return;
  }
  i -= 128;
  if (i < 12800) {                      // tH[o][h] = s1 * w1[80..95]·encH(h)
    int o = i / 200, h = i - o*200;
    float a = 0.f;
    for (int j = 0; j < 8; ++j) {
      float dv = expf((float)(2*j) * (-0.5756462732485115f));
      float t  = (float)h * dv;
      a += w1[o*112 + 80 + j] * sinf(t) + w1[o*112 + 88 + j] * cosf(t);
    }
    ws[OFF_TH + i] = (g1[o]*RS) * a;
    return;
  }
  i -= 12800;
  if (i < 11264) {                      // tW[o][w] = s1 * w1[96..111]·encW(w)
    int o = i / 176, w = i - o*176;
    float a = 0.f;
    for (int j = 0; j < 8; ++j) {
      float dv = expf((float)(2*j) * (-0.5756462732485115f));
      float t  = (float)w * dv;
      a += w1[o*112 + 96 + j] * sinf(t) + w1[o*112 + 104 + j] * cosf(t);
    }
    ws[OFF_TW + i] = (g1[o]*RS) * a;
    return;
  }
  i -= 11264;
  if (i < 2048) {                       // w2ft[c][o2] = w2[o2][c] * s2[o2]
    int c = i >> 5, o = i & 31;
    ws[OFF_W2F + i] = w2[o*64 + c] * (g2[o] * RS);
    return;
  }
  i -= 2048;
  if (i < 32) { ws[OFF_B2F + i] = b2[i]*(g2[i]*RS) + be2[i]; return; }
  i -= 32;
  if (i < 32) { ws[OFF_W3F + i] = w3[i]; }
}

// ---------------- pass 1: MLP for BOTH inputs; wave = (depth, channel-half) ----------------
// inp=1 (x1): writes f1 = x1 * wt1, layout [n][cd4][hw][4]
// inp=0 (x0): writes wtT[d][n][hw]
__global__ __launch_bounds__(256)
void mlp_kernel(const float* __restrict__ x0, const float* __restrict__ x1,
                const float* __restrict__ wtab, float* __restrict__ f1out,
                float* __restrict__ wtT) {
  __shared__ float h1s[2][64][64];   // [d][c][px] 32 KB
  __shared__ float lgp[2][2][64];    // [d][half][px]
  __shared__ float wts[2][64];

  const int tix = threadIdx.x;
  const int px  = tix & 63;
  const int wv   = __builtin_amdgcn_readfirstlane(tix >> 6);  // uniform wave id
  const int d    = wv >> 1;
  const int half = wv & 1;
  const int n   = blockIdx.y;
  const int inp = blockIdx.z;
  const int hw  = blockIdx.x * 64 + px;
  const int h   = hw / 176;
  const int w   = hw - h * 176;
  const float* xn = (inp ? x1 : x0) + (size_t)n * CD * HW;

  // ---- layer 1: this wave computes channels [og, og+32) for depth d ----
  const int og = half * 32;
  float acc[32];
#pragma unroll
  for (int oi = 0; oi < 32; ++oi) {
    const int o = og + oi;
    acc[oi] = wtab[OFF_TD + d*64 + o] + wtab[OFF_TH + o*200 + h] + wtab[OFF_TW + o*176 + w];
  }
#pragma unroll 4
  for (int c = 0; c < 64; ++c) {
    const float xv = xn[(size_t)(c*2 + d)*HW + hw];
    const float* wr = wtab + OFF_W1F + c*64 + og;   // wave-uniform -> s_load
#pragma unroll
    for (int oi = 0; oi < 32; ++oi)
      acc[oi] = fmaf(wr[oi], xv, acc[oi]);
  }
#pragma unroll
  for (int oi = 0; oi < 32; ++oi)
    h1s[d][og + oi][px] = lrelu(acc[oi]);
  __syncthreads();

  // ---- layer 2: this wave computes o2 in [o2g, o2g+16) for depth d; fold layer 3 ----
  const int o2g = half * 16;
  float acc2[16];
#pragma unroll
  for (int oi = 0; oi < 16; ++oi)
    acc2[oi] = wtab[OFF_B2F + o2g + oi];
#pragma unroll 4
  for (int c = 0; c < 64; ++c) {
    const float a = h1s[d][c][px];
    const float* wr = wtab + OFF_W2F + c*32 + o2g;  // wave-uniform -> s_load
#pragma unroll
    for (int oi = 0; oi < 16; ++oi)
      acc2[oi] = fmaf(wr[oi], a, acc2[oi]);
  }
  float lp = 0.f;
#pragma unroll
  for (int oi = 0; oi < 16; ++oi)
    lp = fmaf(wtab[OFF_W3F + o2g + oi], lrelu(acc2[oi]), lp);
  lgp[d][half][px] = lp;
  __syncthreads();

  // ---- softmax over the 2 depths (b3 cancels) ----
  if (tix < 128) {
    const int dd = tix >> 6;
    const float ld = lgp[dd][0][px]     + lgp[dd][1][px];
    const float lo = lgp[1-dd][0][px]   + lgp[1-dd][1][px];
    const float wt = 1.f / (1.f + expf(lo - ld));
    wts[dd][px] = wt;
    if (inp == 0) wtT[(size_t)(dd*4 + n)*HW + hw] = wt;
  }
  if (inp == 0) return;      // block-uniform branch

  __syncthreads();
  const float w0  = wts[0][px];
  const float w1v = wts[1][px];
#pragma unroll
  for (int i = 0; i < 8; ++i) {
    const int k = wv*8 + i, cd0 = k*4;
    float4 v;
    v.x = xn[(size_t)(cd0+0)*HW + hw] * w0;
    v.y = xn[(size_t)(cd0+1)*HW + hw] * w1v;
    v.z = xn[(size_t)(cd0+2)*HW + hw] * w0;
    v.w = xn[(size_t)(cd0+3)*HW + hw] * w1v;
    *(float4*)(f1out + (((size_t)n*32 + k)*HW + hw)*4) = v;
  }
}

// ---------------- pass 2: pure memory — out = max(x0*wt0, bilinear(rot(f1))) ----------------
__global__ __launch_bounds__(256)
void gather_max_kernel(const float* __restrict__ x0,
                       const float* __restrict__ f1,
                       const float* __restrict__ wtT,
                       const float* __restrict__ tp,
                       float* __restrict__ out) {
  const int tix = threadIdx.x;
  const int px  = tix & 63;
  const int q   = tix >> 6;
  const int n   = blockIdx.y;
  const int hw  = blockIdx.x * 64 + px;
  const int h   = hw / 176;
  const int w   = hw - h * 176;
  const float* xn = x0 + (size_t)n * CD * HW;
  const float w0  = wtT[(size_t)(0 + n)*HW + hw];
  const float w1v = wtT[(size_t)(4 + n)*HW + hw];

  // rotated sample position (faithful two-step rotation like the reference)
  const float thp = tp[n*2 + 0], thc = tp[n*2 + 1];
  const float gx = 0.2f + 0.4f * (float)w;
  const float gy = -39.8f + 0.4f * (float)h;
  const float c1 = cosf(thc),  s1v = sinf(thc);
  const float p1x = gx*c1 - gy*s1v;
  const float p1y = gx*s1v + gy*c1;
  const float c2 = cosf(-thp), s2v = sinf(-thp);
  const float p2x = p1x*c2 - p1y*s2v;
  const float p2y = p1x*s2v + p1y*c2;
  const float xi = p2x / 0.05f / 8.f;
  const float yi = (p2y - (-40.f)) / 0.05f / 8.f;

  const float xf = floorf(xi), yf = floorf(yi);
  const int x0i = (int)xf, y0i = (int)yf;
  const int x0c = min(max(x0i,     0), 175);
  const int x1c = min(max(x0i + 1, 0), 175);
  const int y0c = min(max(y0i,     0), 199);
  const int y1c = min(max(y0i + 1, 0), 199);
  const float x0f = (float)x0c, x1f = (float)x1c;
  const float y0f = (float)y0c, y1f = (float)y1c;
  const float wa = (x1f - xi) * (y1f - yi);
  const float wb = (x1f - xi) * (yi - y0f);
  const float wc = (xi - x0f) * (y1f - yi);
  const float wd = (xi - x0f) * (yi - y0f);
  const int ta = y0c*176 + x0c, tb = y1c*176 + x0c;
  const int tc = y0c*176 + x1c, td = y1c*176 + x1c;

#pragma unroll
  for (int i = 0; i < 8; ++i) {
    const int cd4 = q*8 + i;
    const int cd0 = cd4*4;
    const float* fb = f1 + ((size_t)n*32 + cd4)*HW*4;
    const float4 Ia = *(const float4*)(fb + (size_t)ta*4);
    const float4 Ib = *(const float4*)(fb + (size_t)tb*4);
    const float4 Ic = *(const float4*)(fb + (size_t)tc*4);
    const float4 Id = *(const float4*)(fb + (size_t)td*4);
    float4 sv;
    sv.x = Ia.x*wa + Ib.x*wb + Ic.x*wc + Id.x*wd;
    sv.y = Ia.y*wa + Ib.y*wb + Ic.y*wc + Id.y*wd;
    sv.z = Ia.z*wa + Ib.z*wb + Ic.z*wc + Id.z*wd;
    sv.w = Ia.w*wa + Ib.w*wb + Ic.w*wc + Id.w*wd;

    const float f00 = xn[(size_t)(cd0+0)*HW + hw] * w0;
    const float f01 = xn[(size_t)(cd0+1)*HW + hw] * w1v;
    const float f02 = xn[(size_t)(cd0+2)*HW + hw] * w0;
    const float f03 = xn[(size_t)(cd0+3)*HW + hw] * w1v;

    float* op = out + ((size_t)n*CD + cd0)*HW + hw;
    op[0]            = fmaxf(f00, sv.x);
    op[HW]           = fmaxf(f01, sv.y);
    op[2*(size_t)HW] = fmaxf(f02, sv.z);
    op[3*(size_t)HW] = fmaxf(f03, sv.w);
  }
}

extern "C" void kernel_launch(void* const* d_in, const int* in_sizes, int n_in,
                              void* d_out, int out_size, void* d_ws, size_t ws_size,
                              hipStream_t stream) {
  const float* x0  = (const float*)d_in[0];
  const float* x1  = (const float*)d_in[1];
  const float* tp  = (const float*)d_in[2];
  const float* w1  = (const float*)d_in[3];
  const float* b1  = (const float*)d_in[4];
  const float* g1  = (const float*)d_in[5];
  const float* be1 = (const float*)d_in[6];
  const float* w2  = (const float*)d_in[7];
  const float* b2  = (const float*)d_in[8];
  const float* g2  = (const float*)d_in[9];
  const float* be2 = (const float*)d_in[10];
  const float* w3  = (const float*)d_in[11];
  const float* b3  = (const float*)d_in[12];
  float* ws = (float*)d_ws;

  setup_kernel<<<119, 256, 0, stream>>>(w1, b1, g1, be1, w2, b2, g2, be2, w3, b3, ws);

  dim3 g1d(550, 4, 2);   // 64 px per block, n, input
  mlp_kernel<<<g1d, 256, 0, stream>>>(x0, x1, ws, ws + OFF_F1, ws + OFF_WT);

  dim3 g2d(550, 4);      // 64 px per block x 4 channel-quarters, n
  gather_max_kernel<<<g2d, 256, 0, stream>>>(x0, ws + OFF_F1, ws + OFF_WT, tp, (float*)d_out);
}

// Round 5
// 120.866 us; speedup vs baseline: 1.5225x; 1.3399x over previous
//
#include <hip/hip_runtime.h>
#include <cmath>

#define HW   35200          // 200*176
#define CD   128            // C*D

typedef short bf16x8 __attribute__((ext_vector_type(8)));
typedef float f32x4  __attribute__((ext_vector_type(4)));

// ---- workspace float offsets ----
#define OFF_W1B   0         // w1b frag-layout bf16 [3 kh][4 nt][64 lane][8 e]  (6144 bf16 = 3072 f)
#define OFF_W2B   3072      // w2b frag-layout bf16 [2 kh][2 nt][64][8]         (2048 bf16 = 1024 f)
#define OFF_TD    4096      // tD[d][o] fp32 (b1,be1,BN folded)                 (128 f)
#define OFF_B2F   4224      // fp32 (b2,be2,BN folded)                          (32 f)
#define OFF_W3F   4256      // fp32                                             (32 f)
#define OFF_PE    4352      // peHW[hw][32] bf16                                (1126400 bf16 = 563200 f)
#define OFF_WT    567552    // wtT[d][n][hw] fp32                               (281600 f)
#define OFF_F1    849152    // f1 [n][32][HW][4] fp32                           (18022400 f)

__device__ __forceinline__ float lrelu(float v) { return v >= 0.f ? v : 0.01f * v; }
__device__ __forceinline__ unsigned short f2bf(float f) {   // RNE fp32->bf16
  unsigned u = __float_as_uint(f);
  u = (u + 0x7fffu + ((u >> 16) & 1u)) >> 16;
  return (unsigned short)u;
}

// ---------------- setup: BN-folded bf16 weight frags, tD, PE table ----------------
__global__ void setup_kernel(const float* __restrict__ w1, const float* __restrict__ b1,
                             const float* __restrict__ g1, const float* __restrict__ be1,
                             const float* __restrict__ w2, const float* __restrict__ b2,
                             const float* __restrict__ g2, const float* __restrict__ be2,
                             const float* __restrict__ w3, const float* __restrict__ b3,
                             float* __restrict__ ws) {
  const float RS = rsqrtf(1.0f + 1e-5f);
  unsigned short* w1b = (unsigned short*)(ws + OFF_W1B);
  unsigned short* w2b = (unsigned short*)(ws + OFF_W2B);
  unsigned short* pe  = (unsigned short*)(ws + OFF_PE);
  int i = blockIdx.x * blockDim.x + threadIdx.x;
  if (i < 6144) {                  // w1b: B[k][n], k=kh*32+(l>>4)*8+e, n=nt*16+(l&15)
    int e = i & 7, l = (i >> 3) & 63, nt = (i >> 9) & 3, kh = i >> 11;
    int n = nt * 16 + (l & 15);
    int k = kh * 32 + (l >> 4) * 8 + e;
    int col = (kh < 2) ? k : (80 + (k - 64));   // PE slots s=k-64 map to w1 cols 80..111
    w1b[i] = f2bf(w1[n * 112 + col] * (g1[n] * RS));
    return;
  }
  i -= 6144;
  if (i < 2048) {                  // w2b
    int e = i & 7, l = (i >> 3) & 63, nt = (i >> 9) & 1, kh = i >> 10;
    int n = nt * 16 + (l & 15);
    int k = kh * 32 + (l >> 4) * 8 + e;
    w2b[i] = f2bf(w2[n * 64 + k] * (g2[n] * RS));
    return;
  }
  i -= 2048;
  if (i < 128) {                   // tD[d][o] = s1*(b1 + w1[64..79]·encD(d)) + be1
    int d = i >> 6, o = i & 63;
    float a = 0.f;
    for (int j = 0; j < 8; ++j) {
      float dv = expf((float)(2 * j) * (-0.5756462732485115f));
      float t  = (float)d * dv;
      a += w1[o * 112 + 64 + j] * sinf(t) + w1[o * 112 + 72 + j] * cosf(t);
    }
    ws[OFF_TD + d * 64 + o] = (g1[o] * RS) * (b1[o] + a) + be1[o];
    return;
  }
  i -= 128;
  if (i < 32) { ws[OFF_B2F + i] = b2[i] * (g2[i] * RS) + be2[i]; return; }
  i -= 32;
  if (i < 32) { ws[OFF_W3F + i] = w3[i]; return; }
  i -= 32;
  if (i < 563200) {                // peHW[hw][32]: slots 0-7 sinH,8-15 cosH,16-23 sinW,24-31 cosW
    int hw = i >> 4, j = i & 15;
    int h = hw / 176, w = hw - h * 176;
    int jj = j & 7;
    float dv = expf((float)(2 * jj) * (-0.5756462732485115f));
    if (j < 8) {
      float t = (float)h * dv;
      pe[hw * 32 + jj]      = f2bf(sinf(t));
      pe[hw * 32 + 8 + jj]  = f2bf(cosf(t));
    } else {
      float t = (float)w * dv;
      pe[hw * 32 + 16 + jj] = f2bf(sinf(t));
      pe[hw * 32 + 24 + jj] = f2bf(cosf(t));
    }
  }
}

// ---------------- pass 1: MFMA MLP for both inputs ----------------
// Block: 64 px, 128 rows (row = d*64+px), K=96 (64 x-ch + 32 PE-ch).
// inp=1: writes f1 = x1*wt (rebuilt from LDS bf16 copy of x1); inp=0: writes wtT.
__global__ __launch_bounds__(256)
void mlp_kernel(const float* __restrict__ x0, const float* __restrict__ x1,
                const float* __restrict__ wtab, float* __restrict__ f1out,
                float* __restrict__ wtT) {
  __shared__ alignas(16) unsigned short As[12 * 128 * 8];  // [kgrp][row][8] bf16, 24 KB
  __shared__ alignas(16) unsigned short Hs[8 * 128 * 8];   // h1 in same layout, 16 KB
  __shared__ float lg[128];
  __shared__ float wts[2][64];

  const int t    = threadIdx.x;
  const int lane = t & 63;
  const int wv   = __builtin_amdgcn_readfirstlane(t >> 6);
  const int px   = lane;
  const int n    = blockIdx.y;
  const int inp  = blockIdx.z;
  const int hw0  = blockIdx.x * 64;
  const float* xn = (inp ? x1 : x0) + (size_t)n * CD * HW;
  const unsigned short* w1bu = (const unsigned short*)(wtab + OFF_W1B);
  const unsigned short* w2bu = (const unsigned short*)(wtab + OFF_W2B);
  const unsigned short* peg  = (const unsigned short*)(wtab + OFF_PE);

  // ---- stage x (fp32->bf16) and PE rows into As ----
#pragma unroll
  for (int i2 = 0; i2 < 4; ++i2) {
    const int md = wv * 4 + i2, d = md & 1, m = md >> 1;   // kgrp m, depth d
    float v[8];
#pragma unroll
    for (int e = 0; e < 8; ++e)
      v[e] = xn[(size_t)((m * 8 + e) * 2 + d) * HW + hw0 + px];
    uint4 uu;
    uu.x = (unsigned)f2bf(v[0]) | ((unsigned)f2bf(v[1]) << 16);
    uu.y = (unsigned)f2bf(v[2]) | ((unsigned)f2bf(v[3]) << 16);
    uu.z = (unsigned)f2bf(v[4]) | ((unsigned)f2bf(v[5]) << 16);
    uu.w = (unsigned)f2bf(v[6]) | ((unsigned)f2bf(v[7]) << 16);
    *(uint4*)&As[(unsigned)(m * 128 + d * 64 + px) * 8] = uu;
  }
  if (t < 64) {                                            // PE channels (same for both depths)
    const uint4* pp = (const uint4*)(peg + (size_t)(hw0 + t) * 32);
#pragma unroll
    for (int j = 0; j < 4; ++j) {
      uint4 v = pp[j];
      *(uint4*)&As[(unsigned)((8 + j) * 128 + t) * 8]      = v;
      *(uint4*)&As[(unsigned)((8 + j) * 128 + 64 + t) * 8] = v;
    }
  }
  __syncthreads();

  // ---- layer 1: rows[M=128] x K=96 x N=64; wave owns row-tiles {2wv, 2wv+1} ----
  const int rtb = wv * 2, dw = wv >> 1;   // rows [wv*32, wv*32+32), depth dw
  f32x4 acc[2][4];
#pragma unroll
  for (int nt = 0; nt < 4; ++nt) {
    const float tdv = wtab[OFF_TD + dw * 64 + nt * 16 + (lane & 15)];
    acc[0][nt] = (f32x4){tdv, tdv, tdv, tdv};
    acc[1][nt] = acc[0][nt];
  }
#pragma unroll
  for (int kh = 0; kh < 3; ++kh) {
    const bf16x8 a0 = *(const bf16x8*)&As[(unsigned)((kh * 4 + (lane >> 4)) * 128 + (rtb + 0) * 16 + (lane & 15)) * 8];
    const bf16x8 a1 = *(const bf16x8*)&As[(unsigned)((kh * 4 + (lane >> 4)) * 128 + (rtb + 1) * 16 + (lane & 15)) * 8];
#pragma unroll
    for (int nt = 0; nt < 4; ++nt) {
      const bf16x8 b = *(const bf16x8*)&w1bu[(unsigned)((kh * 4 + nt) * 64 + lane) * 8];
      acc[0][nt] = __builtin_amdgcn_mfma_f32_16x16x32_bf16(a0, b, acc[0][nt], 0, 0, 0);
      acc[1][nt] = __builtin_amdgcn_mfma_f32_16x16x32_bf16(a1, b, acc[1][nt], 0, 0, 0);
    }
  }
  // lrelu + write h1 (bf16) to Hs; D layout: row=(l>>4)*4+r, col=l&15
#pragma unroll
  for (int rti = 0; rti < 2; ++rti)
#pragma unroll
    for (int nt = 0; nt < 4; ++nt)
#pragma unroll
      for (int r = 0; r < 4; ++r) {
        const int o   = nt * 16 + (lane & 15);
        const int row = (rtb + rti) * 16 + (lane >> 4) * 4 + r;
        Hs[(unsigned)((o >> 3) * 128 + row) * 8 + (o & 7)] = f2bf(lrelu(acc[rti][nt][r]));
      }
  __syncthreads();

  // ---- layer 2: K=64 x N=32 ----
  f32x4 acc2[2][2];
#pragma unroll
  for (int nt = 0; nt < 2; ++nt) {
    const float bv = wtab[OFF_B2F + nt * 16 + (lane & 15)];
    acc2[0][nt] = (f32x4){bv, bv, bv, bv};
    acc2[1][nt] = acc2[0][nt];
  }
#pragma unroll
  for (int kh = 0; kh < 2; ++kh) {
    const bf16x8 a0 = *(const bf16x8*)&Hs[(unsigned)((kh * 4 + (lane >> 4)) * 128 + (rtb + 0) * 16 + (lane & 15)) * 8];
    const bf16x8 a1 = *(const bf16x8*)&Hs[(unsigned)((kh * 4 + (lane >> 4)) * 128 + (rtb + 1) * 16 + (lane & 15)) * 8];
#pragma unroll
    for (int nt = 0; nt < 2; ++nt) {
      const bf16x8 b = *(const bf16x8*)&w2bu[(unsigned)((kh * 2 + nt) * 64 + lane) * 8];
      acc2[0][nt] = __builtin_amdgcn_mfma_f32_16x16x32_bf16(a0, b, acc2[0][nt], 0, 0, 0);
      acc2[1][nt] = __builtin_amdgcn_mfma_f32_16x16x32_bf16(a1, b, acc2[1][nt], 0, 0, 0);
    }
  }

  // ---- layer 3 + logit reduce (b3 cancels in 2-way softmax) ----
  const float w3a = wtab[OFF_W3F + (lane & 15)];
  const float w3b = wtab[OFF_W3F + 16 + (lane & 15)];
#pragma unroll
  for (int rti = 0; rti < 2; ++rti)
#pragma unroll
    for (int r = 0; r < 4; ++r) {
      float p = w3a * lrelu(acc2[rti][0][r]) + w3b * lrelu(acc2[rti][1][r]);
      p += __shfl_xor(p, 1);
      p += __shfl_xor(p, 2);
      p += __shfl_xor(p, 4);
      p += __shfl_xor(p, 8);
      if ((lane & 15) == 0) lg[(rtb + rti) * 16 + (lane >> 4) * 4 + r] = p;
    }
  __syncthreads();

  // ---- softmax over 2 depths ----
  if (t < 128) {
    const int pp = t & 63, dd = t >> 6;
    const float lm = lg[dd * 64 + pp], lo = lg[(1 - dd) * 64 + pp];
    const float wtv = 1.f / (1.f + expf(lo - lm));
    wts[dd][pp] = wtv;
    if (inp == 0) wtT[(size_t)(dd * 4 + n) * HW + hw0 + pp] = wtv;
  }
  if (inp) {                       // block-uniform branch
    __syncthreads();
    const float w0 = wts[0][px], w1v = wts[1][px];
#pragma unroll
    for (int i2 = 0; i2 < 8; ++i2) {
      const int k = wv * 8 + i2;   // cd4 index: planes 4k..4k+3 = (c=2k,d0),(2k,d1),(2k+1,d0),(2k+1,d1)
      const unsigned ua = *(const unsigned*)&As[(unsigned)((k >> 2) * 128 + px) * 8 + ((2 * k) & 7)];
      const unsigned ub = *(const unsigned*)&As[(unsigned)((k >> 2) * 128 + 64 + px) * 8 + ((2 * k) & 7)];
      float4 v;
      v.x = __uint_as_float(ua << 16)          * w0;
      v.y = __uint_as_float(ub << 16)          * w1v;
      v.z = __uint_as_float(ua & 0xffff0000u)  * w0;
      v.w = __uint_as_float(ub & 0xffff0000u)  * w1v;
      *(float4*)(f1out + (((size_t)n * 32 + k) * HW + hw0 + px) * 4) = v;
    }
  }
}

// ---------------- pass 2: pure memory — out = max(x0*wt0, bilinear(rot(f1))) ----------------
__global__ __launch_bounds__(256)
void gather_max_kernel(const float* __restrict__ x0,
                       const float* __restrict__ f1,
                       const float* __restrict__ wtT,
                       const float* __restrict__ tp,
                       float* __restrict__ out) {
  const int tix = threadIdx.x;
  const int px  = tix & 63;
  const int q   = tix >> 6;
  const int n   = blockIdx.y;
  const int hw  = blockIdx.x * 64 + px;
  const int h   = hw / 176;
  const int w   = hw - h * 176;
  const float* xn = x0 + (size_t)n * CD * HW;
  const float w0  = wtT[(size_t)(0 + n) * HW + hw];
  const float w1v = wtT[(size_t)(4 + n) * HW + hw];

  const float thp = tp[n * 2 + 0], thc = tp[n * 2 + 1];
  const float gx = 0.2f + 0.4f * (float)w;
  const float gy = -39.8f + 0.4f * (float)h;
  const float c1 = cosf(thc),  s1v = sinf(thc);
  const float p1x = gx * c1 - gy * s1v;
  const float p1y = gx * s1v + gy * c1;
  const float c2 = cosf(-thp), s2v = sinf(-thp);
  const float p2x = p1x * c2 - p1y * s2v;
  const float p2y = p1x * s2v + p1y * c2;
  const float xi = p2x / 0.05f / 8.f;
  const float yi = (p2y - (-40.f)) / 0.05f / 8.f;

  const float xf = floorf(xi), yf = floorf(yi);
  const int x0i = (int)xf, y0i = (int)yf;
  const int x0c = min(max(x0i,     0), 175);
  const int x1c = min(max(x0i + 1, 0), 175);
  const int y0c = min(max(y0i,     0), 199);
  const int y1c = min(max(y0i + 1, 0), 199);
  const float x0f = (float)x0c, x1f = (float)x1c;
  const float y0f = (float)y0c, y1f = (float)y1c;
  const float wa = (x1f - xi) * (y1f - yi);
  const float wb = (x1f - xi) * (yi - y0f);
  const float wc = (xi - x0f) * (y1f - yi);
  const float wd = (xi - x0f) * (yi - y0f);
  const int ta = y0c * 176 + x0c, tb = y1c * 176 + x0c;
  const int tc = y0c * 176 + x1c, td = y1c * 176 + x1c;

#pragma unroll
  for (int i = 0; i < 8; ++i) {
    const int cd4 = q * 8 + i;
    const int cd0 = cd4 * 4;
    const float* fb = f1 + ((size_t)n * 32 + cd4) * HW * 4;
    const float4 Ia = *(const float4*)(fb + (size_t)ta * 4);
    const float4 Ib = *(const float4*)(fb + (size_t)tb * 4);
    const float4 Ic = *(const float4*)(fb + (size_t)tc * 4);
    const float4 Id = *(const float4*)(fb + (size_t)td * 4);
    float4 sv;
    sv.x = Ia.x * wa + Ib.x * wb + Ic.x * wc + Id.x * wd;
    sv.y = Ia.y * wa + Ib.y * wb + Ic.y * wc + Id.y * wd;
    sv.z = Ia.z * wa + Ib.z * wb + Ic.z * wc + Id.z * wd;
    sv.w = Ia.w * wa + Ib.w * wb + Ic.w * wc + Id.w * wd;

    const float f00 = xn[(size_t)(cd0 + 0) * HW + hw] * w0;
    const float f01 = xn[(size_t)(cd0 + 1) * HW + hw] * w1v;
    const float f02 = xn[(size_t)(cd0 + 2) * HW + hw] * w0;
    const float f03 = xn[(size_t)(cd0 + 3) * HW + hw] * w1v;

    float* op = out + ((size_t)n * CD + cd0) * HW + hw;
    op[0]              = fmaxf(f00, sv.x);
    op[HW]             = fmaxf(f01, sv.y);
    op[2 * (size_t)HW] = fmaxf(f02, sv.z);
    op[3 * (size_t)HW] = fmaxf(f03, sv.w);
  }
}

extern "C" void kernel_launch(void* const* d_in, const int* in_sizes, int n_in,
                              void* d_out, int out_size, void* d_ws, size_t ws_size,
                              hipStream_t stream) {
  const float* x0  = (const float*)d_in[0];
  const float* x1  = (const float*)d_in[1];
  const float* tp  = (const float*)d_in[2];
  const float* w1  = (const float*)d_in[3];
  const float* b1  = (const float*)d_in[4];
  const float* g1  = (const float*)d_in[5];
  const float* be1 = (const float*)d_in[6];
  const float* w2  = (const float*)d_in[7];
  const float* b2  = (const float*)d_in[8];
  const float* g2  = (const float*)d_in[9];
  const float* be2 = (const float*)d_in[10];
  const float* w3  = (const float*)d_in[11];
  const float* b3  = (const float*)d_in[12];
  float* ws = (float*)d_ws;

  setup_kernel<<<2233, 256, 0, stream>>>(w1, b1, g1, be1, w2, b2, g2, be2, w3, b3, ws);

  dim3 g1d(550, 4, 2);   // 64 px per block, n, input
  mlp_kernel<<<g1d, 256, 0, stream>>>(x0, x1, ws, ws + OFF_F1, ws + OFF_WT);

  dim3 g2d(550, 4);      // 64 px x 4 channel-quarters, n
  gather_max_kernel<<<g2d, 256, 0, stream>>>(x0, ws + OFF_F1, ws + OFF_WT, tp, (float*)d_out);
}